// Round 20
// baseline (146.933 us; speedup 1.0000x reference)
//
#include <hip/hip_runtime.h>
#include <cstdint>

// N=4096 windows, T=33, C=96, H=6, HD=16.
// ws layout v5:
//   qf  : fp32 q[n][h][t][d]          4096*3168 floats  = 51.9 MB
//   kvh : bf16, window stride 7008 u16 = K[h][t][d] (3168) + V^T[h][d][t]
//         (row stride 40 u16 -> 640/head, 3840) = 57.4 MB. Total 109.3 MB.
// GEMMs: MFMA 16x16x32 bf16 split-precision (hi+lo).
// v19 changes (GEMM-side only):
//  * qkv split into q_mfma (M128, 6 tiles) + kv_mfma (M64, 6+6 tiles):
//    A read+converted 2x instead of 3x (-52MB fp32 traffic).
//  * proj_mfma: per-kstep A staging (LDS 53.2KB -> 20.5KB, occ 3->8 blocks).
// Attn v17 unchanged (MFMA attn, shfl P-repack, uniform bias build).

static constexpr int NWIN = 4096;
static constexpr int MROWS = NWIN * 33;          // 135168 = 1056*128
static constexpr float SCALE = 0.25f;            // HD^-0.5
static constexpr int KVSTRIDE = 7008;            // u16 per window in kvh

using short8 = __attribute__((ext_vector_type(8))) short;
using f32x4  = __attribute__((ext_vector_type(4))) float;

__device__ __forceinline__ unsigned short f2bf(float f) {
  unsigned u = __float_as_uint(f);
  u += 0x7fffu + ((u >> 16) & 1u);
  return (unsigned short)(u >> 16);
}
__device__ __forceinline__ float bf2f(unsigned short h) {
  return __uint_as_float(((unsigned)h) << 16);
}
__device__ __forceinline__ float bflo(unsigned u) { return __uint_as_float(u << 16); }
__device__ __forceinline__ float bfhi(unsigned u) { return __uint_as_float(u & 0xffff0000u); }

// ---------------- K0: qkv_w -> B-fragments in d_out ----------------
__global__ __launch_bounds__(256) void conv_w_qkv(
    const float* __restrict__ W, unsigned* __restrict__ frag) {
  const int fp = blockIdx.x;                     // 108 = 3 ksteps*18 cf*2 hl
  const int kstep = fp / 36;
  const int r = fp - kstep*36;
  const int cf = r >> 1, hl = r & 1;
  const int t = threadIdx.x, lane = t >> 2, d = t & 3;
  const int k = kstep*32 + (lane >> 4)*8 + d*2;
  const int n = cf*16 + (lane & 15);
  float w0 = W[k*288 + n], w1 = W[(k+1)*288 + n];
  if (hl) { w0 -= bf2f(f2bf(w0)); w1 -= bf2f(f2bf(w1)); }
  frag[fp*256 + t] = (unsigned)f2bf(w0) | ((unsigned)f2bf(w1) << 16);
}

// ---------------- K2b: proj_w -> B-fragments at start of (dead) kvh ----
__global__ __launch_bounds__(256) void conv_w_proj(
    const float* __restrict__ W, unsigned* __restrict__ frag) {
  const int fp = blockIdx.x;                     // 36 = 3 ksteps*6 cf*2 hl
  const int kstep = fp / 12;
  const int r = fp - kstep*12;
  const int cf = r >> 1, hl = r & 1;
  const int t = threadIdx.x, lane = t >> 2, d = t & 3;
  const int k = kstep*32 + (lane >> 4)*8 + d*2;
  const int n = cf*16 + (lane & 15);
  float w0 = W[k*96 + n], w1 = W[(k+1)*96 + n];
  if (hl) { w0 -= bf2f(f2bf(w0)); w1 -= bf2f(f2bf(w1)); }
  frag[fp*256 + t] = (unsigned)f2bf(w0) | ((unsigned)f2bf(w1) << 16);
}

// ---------------- K1a: Q projection (M128, 6 tiles) ----------------
__global__ __launch_bounds__(256) void q_mfma(
    const float* __restrict__ A, const unsigned* __restrict__ frag,
    const float* __restrict__ bias, float* __restrict__ qf) {
  __shared__ __align__(16) unsigned short sBuf[10240];   // 20480 B
  unsigned short* sAh = sBuf;          // [128][40]
  unsigned short* sAl = sBuf + 5120;
  const int tid = threadIdx.x;
  const int w = tid >> 6, l = tid & 63;
  const int m0 = blockIdx.x * 128;
  f32x4 acc[2][6];
  #pragma unroll
  for (int rf = 0; rf < 2; ++rf)
    #pragma unroll
    for (int cf = 0; cf < 6; ++cf) acc[rf][cf] = (f32x4){0.f,0.f,0.f,0.f};

  #pragma unroll
  for (int kstep = 0; kstep < 3; ++kstep) {
    short8 bh[6], bl[6];
    #pragma unroll
    for (int cf = 0; cf < 6; ++cf) {
      const int fp = (kstep*18 + cf)*2;
      bh[cf] = *(const short8*)((const char*)frag + (size_t)fp*1024 + l*16);
      bl[cf] = *(const short8*)((const char*)frag + (size_t)fp*1024 + 1024 + l*16);
    }
    __syncthreads();
    #pragma unroll
    for (int it2 = 0; it2 < 4; ++it2) {
      const int idx = tid + it2*256;
      const int row = idx >> 3, q = idx & 7;
      const float4 v = *(const float4*)(A + (size_t)(m0+row)*96 + kstep*32 + q*4);
      ushort4 hv, lv;
      hv.x = f2bf(v.x); hv.y = f2bf(v.y); hv.z = f2bf(v.z); hv.w = f2bf(v.w);
      lv.x = f2bf(v.x - bf2f(hv.x)); lv.y = f2bf(v.y - bf2f(hv.y));
      lv.z = f2bf(v.z - bf2f(hv.z)); lv.w = f2bf(v.w - bf2f(hv.w));
      *(ushort4*)&sAh[row*40 + q*4] = hv;
      *(ushort4*)&sAl[row*40 + q*4] = lv;
    }
    __syncthreads();
    #pragma unroll
    for (int rf = 0; rf < 2; ++rf) {
      const int row = w*32 + rf*16 + (l & 15);
      const int off = row*40 + (l >> 4)*8;
      const short8 ah = *(const short8*)&sAh[off];
      const short8 al = *(const short8*)&sAl[off];
      #pragma unroll
      for (int cf = 0; cf < 6; ++cf) {
        acc[rf][cf] = __builtin_amdgcn_mfma_f32_16x16x32_bf16(ah, bh[cf], acc[rf][cf], 0,0,0);
        acc[rf][cf] = __builtin_amdgcn_mfma_f32_16x16x32_bf16(al, bh[cf], acc[rf][cf], 0,0,0);
        acc[rf][cf] = __builtin_amdgcn_mfma_f32_16x16x32_bf16(ah, bl[cf], acc[rf][cf], 0,0,0);
      }
    }
  }
  const int col = l & 15;
  #pragma unroll
  for (int cf = 0; cf < 6; ++cf) {
    const float bv = bias[cf*16 + col];
    #pragma unroll
    for (int rf = 0; rf < 2; ++rf)
      #pragma unroll
      for (int r = 0; r < 4; ++r) {
        const int m = m0 + w*32 + rf*16 + (l >> 4)*4 + r;
        const int n = m / 33, t = m - n*33;
        qf[(size_t)n*3168 + cf*528 + t*16 + col] = (acc[rf][cf][r] + bv)*SCALE;
      }
  }
}

// ---------------- K1b: K+V projection (M64, 6+6 tiles) ----------------
// grid 2112, block 256 (4 waves, wave = one 16-row frag).
__global__ __launch_bounds__(256) void kv_mfma(
    const float* __restrict__ A, const unsigned* __restrict__ frag,
    const float* __restrict__ bias, unsigned short* __restrict__ kvh) {
  __shared__ __align__(16) unsigned short sBuf[6528];    // 13056 B
  unsigned short* sAh = sBuf;          // [64][40]
  unsigned short* sAl = sBuf + 2560;
  const int tid = threadIdx.x;
  const int w = tid >> 6, l = tid & 63;
  const int m0 = blockIdx.x * 64;
  f32x4 acck[6], accv[6];
  #pragma unroll
  for (int cf = 0; cf < 6; ++cf) {
    acck[cf] = (f32x4){0.f,0.f,0.f,0.f};
    accv[cf] = (f32x4){0.f,0.f,0.f,0.f};
  }
  #pragma unroll
  for (int kstep = 0; kstep < 3; ++kstep) {
    short8 bh[6], bl[6];
    #pragma unroll
    for (int cf = 0; cf < 6; ++cf) {           // K weights (cfg 6..11)
      const int fp = (kstep*18 + 6 + cf)*2;
      bh[cf] = *(const short8*)((const char*)frag + (size_t)fp*1024 + l*16);
      bl[cf] = *(const short8*)((const char*)frag + (size_t)fp*1024 + 1024 + l*16);
    }
    __syncthreads();
    #pragma unroll
    for (int it2 = 0; it2 < 2; ++it2) {
      const int idx = tid + it2*256;           // 0..511
      const int row = idx >> 3, q = idx & 7;   // 64 rows x 8 float4
      const float4 v = *(const float4*)(A + (size_t)(m0+row)*96 + kstep*32 + q*4);
      ushort4 hv, lv;
      hv.x = f2bf(v.x); hv.y = f2bf(v.y); hv.z = f2bf(v.z); hv.w = f2bf(v.w);
      lv.x = f2bf(v.x - bf2f(hv.x)); lv.y = f2bf(v.y - bf2f(hv.y));
      lv.z = f2bf(v.z - bf2f(hv.z)); lv.w = f2bf(v.w - bf2f(hv.w));
      *(ushort4*)&sAh[row*40 + q*4] = hv;
      *(ushort4*)&sAl[row*40 + q*4] = lv;
    }
    __syncthreads();
    const int row = w*16 + (l & 15);
    const int off = row*40 + (l >> 4)*8;
    const short8 ah = *(const short8*)&sAh[off];
    const short8 al = *(const short8*)&sAl[off];
    #pragma unroll
    for (int cf = 0; cf < 6; ++cf) {
      acck[cf] = __builtin_amdgcn_mfma_f32_16x16x32_bf16(ah, bh[cf], acck[cf], 0,0,0);
      acck[cf] = __builtin_amdgcn_mfma_f32_16x16x32_bf16(al, bh[cf], acck[cf], 0,0,0);
      acck[cf] = __builtin_amdgcn_mfma_f32_16x16x32_bf16(ah, bl[cf], acck[cf], 0,0,0);
    }
    #pragma unroll
    for (int cf = 0; cf < 6; ++cf) {           // V weights (cfg 12..17)
      const int fp = (kstep*18 + 12 + cf)*2;
      bh[cf] = *(const short8*)((const char*)frag + (size_t)fp*1024 + l*16);
      bl[cf] = *(const short8*)((const char*)frag + (size_t)fp*1024 + 1024 + l*16);
    }
    #pragma unroll
    for (int cf = 0; cf < 6; ++cf) {
      accv[cf] = __builtin_amdgcn_mfma_f32_16x16x32_bf16(ah, bh[cf], accv[cf], 0,0,0);
      accv[cf] = __builtin_amdgcn_mfma_f32_16x16x32_bf16(al, bh[cf], accv[cf], 0,0,0);
      accv[cf] = __builtin_amdgcn_mfma_f32_16x16x32_bf16(ah, bl[cf], accv[cf], 0,0,0);
    }
  }
  const int col = l & 15;
  // K slab: direct bf16 write [h][t][d]
  #pragma unroll
  for (int cf = 0; cf < 6; ++cf) {
    const float bv = bias[96 + cf*16 + col];
    #pragma unroll
    for (int r = 0; r < 4; ++r) {
      const int m = m0 + w*16 + (l >> 4)*4 + r;
      const int n = m / 33, t = m - n*33;
      kvh[(size_t)n*KVSTRIDE + cf*528 + t*16 + col] = f2bf(acck[cf][r] + bv);
    }
  }
  // V slab: restage into LDS then coalesced V^T write-out
  __syncthreads();
  unsigned short* sV = sBuf;                   // [64][102] = 6528 u16
  #pragma unroll
  for (int cf = 0; cf < 6; ++cf) {
    const float bv = bias[192 + cf*16 + col];
    #pragma unroll
    for (int r = 0; r < 4; ++r) {
      const int row = w*16 + (l >> 4)*4 + r;
      sV[row*102 + cf*16 + col] = f2bf(accv[cf][r] + bv);
    }
  }
  __syncthreads();
  for (int idx = tid; idx < 6144; idx += 256) {
    const int hd = idx >> 6, trow = idx & 63;
    const int m = m0 + trow;
    const int n = m / 33, t = m - n*33;
    kvh[(size_t)n*KVSTRIDE + 3168 + (hd >> 4)*640 + (hd & 15)*40 + t] =
        sV[trow*102 + hd];
  }
}

// ---------------- K2: per-window MFMA attention (v17, unchanged) --------
// grid 4096, block 384 (6 waves, wave = head).
__global__ __launch_bounds__(384) void attn_kernel(
    float* __restrict__ qf, const unsigned short* __restrict__ kvh,
    const int* __restrict__ rel, const float* __restrict__ mask,
    const float* __restrict__ rpet) {
  __shared__ __align__(8) unsigned short sBiasH[7168]; // [h][i][36] + guard
  __shared__ __align__(4) unsigned short sRpe6[920];   // [153][6] bf16
  const int tid = threadIdx.x;
  const int n = blockIdx.x;
  const int l = tid & 63, g = l >> 4, c = l & 15, h = tid >> 6;
  const unsigned short* Kb = kvh + (size_t)n*KVSTRIDE + h*528;
  const unsigned short* Vb = kvh + (size_t)n*KVSTRIDE + 3168 + h*640;
  const float*          Qb = qf  + (size_t)n*3168 + h*528;
  short8 ka[3];
  #pragma unroll
  for (int jt = 0; jt < 3; ++jt)
    ka[jt] = *(const short8*)(Kb + (jt*16 + c)*16 + (g & 1)*8); // K[j][d]
  const short8 vb8 = *(const short8*)(Vb + c*40 + g*8);         // V[j=8g+e][d=c]
  const unsigned short v32u = Vb[c*40 + 32];                    // V[32][d=c]
  float4 qa_[3], qc_[3];
  #pragma unroll
  for (int it = 0; it < 3; ++it) {
    const int i = it*16 + c;
    qa_[it] = make_float4(0.f,0.f,0.f,0.f);
    qc_[it] = make_float4(0.f,0.f,0.f,0.f);
    if (i < 33) {
      qa_[it] = *(const float4*)(Qb + i*16 + (g & 1)*8);
      qc_[it] = *(const float4*)(Qb + i*16 + (g & 1)*8 + 4);
    }
  }
  for (int idx = tid; idx < 918; idx += 384) sRpe6[idx] = f2bf(rpet[idx]);
  __syncthreads();
  {
    const float* gm = mask + (size_t)n*1089;
    const int*   rb = rel  + (size_t)n*3072;
    const unsigned* rp6 = (const unsigned*)sRpe6;
    int   ee[3];
    bool  act[3], rpok[3];
    float mv[3];
    int   xx[3][3];
    #pragma unroll
    for (int q2 = 0; q2 < 3; ++q2) {
      int e = tid + q2*384;
      act[q2] = (e < 1089);
      if (!act[q2]) e = 0;
      ee[q2] = e;
      const int i = e / 33, j = e - i*33;
      rpok[q2] = (i > 0) && (j > 0);
      const int rbase = rpok[q2] ? ((i-1)*32 + (j-1))*3 : 0;
      mv[q2]    = gm[e];
      xx[q2][0] = rb[rbase]*3;
      xx[q2][1] = (rb[rbase+1] + 51)*3;
      xx[q2][2] = (rb[rbase+2] + 102)*3;
    }
    #pragma unroll
    for (int q2 = 0; q2 < 3; ++q2) {
      float b0=0.f, b1=0.f, b2=0.f, b3=0.f, b4=0.f, b5=0.f;
      #pragma unroll
      for (int a = 0; a < 3; ++a) {
        const unsigned u0 = rp6[xx[q2][a]];
        const unsigned u1 = rp6[xx[q2][a]+1];
        const unsigned u2 = rp6[xx[q2][a]+2];
        b0 += bflo(u0); b1 += bfhi(u0);
        b2 += bflo(u1); b3 += bfhi(u1);
        b4 += bflo(u2); b5 += bfhi(u2);
      }
      const float m2 = mv[q2];
      const bool ok = rpok[q2];
      b0 = ok ? b0 + m2 : m2;  b1 = ok ? b1 + m2 : m2;
      b2 = ok ? b2 + m2 : m2;  b3 = ok ? b3 + m2 : m2;
      b4 = ok ? b4 + m2 : m2;  b5 = ok ? b5 + m2 : m2;
      if (act[q2]) {
        const int e = ee[q2];
        const int i = e / 33, j = e - i*33;
        const int bb = i*36 + j;
        sBiasH[bb]        = f2bf(b0);
        sBiasH[bb + 1188] = f2bf(b1);
        sBiasH[bb + 2376] = f2bf(b2);
        sBiasH[bb + 3564] = f2bf(b3);
        sBiasH[bb + 4752] = f2bf(b4);
        sBiasH[bb + 5940] = f2bf(b5);
      }
    }
  }
  const float v32f = bf2f(v32u);
  short8 qfr[3];
  #pragma unroll
  for (int it = 0; it < 3; ++it) {
    const float qv[8] = {qa_[it].x, qa_[it].y, qa_[it].z, qa_[it].w,
                         qc_[it].x, qc_[it].y, qc_[it].z, qc_[it].w};
    short8 t;
    #pragma unroll
    for (int e = 0; e < 8; ++e) {
      const unsigned short hi = f2bf(qv[e]);
      const unsigned short lo = f2bf(qv[e] - bf2f(hi));
      t[e] = (short)((g < 2) ? hi : lo);
    }
    qfr[it] = t;
  }
  __syncthreads();
  const int hbase = h*1188;
  #pragma unroll
  for (int it = 0; it < 3; ++it) {
    const int i  = it*16 + c;
    const int bi = (i < 33) ? i : 0;
    const int bbase = hbase + bi*36;
    float pv[12];
    float mx = -3.4e38f;
    #pragma unroll
    for (int jt = 0; jt < 3; ++jt) {
      const ushort4 bv4 = *(const ushort4*)(sBiasH + bbase + jt*16 + 4*g);
      f32x4 sacc;
      sacc[0] = bf2f(bv4.x); sacc[1] = bf2f(bv4.y);
      sacc[2] = bf2f(bv4.z); sacc[3] = bf2f(bv4.w);
      sacc = __builtin_amdgcn_mfma_f32_16x16x32_bf16(ka[jt], qfr[it], sacc, 0,0,0);
      #pragma unroll
      for (int r = 0; r < 4; ++r) {
        const int j = jt*16 + 4*g + r;
        float sv = sacc[r];
        if (j >= 33) sv = -3.4e38f;
        pv[jt*4+r] = sv;
        mx = fmaxf(mx, sv);
      }
    }
    mx = fmaxf(mx, __shfl_xor(mx, 16));
    mx = fmaxf(mx, __shfl_xor(mx, 32));
    float ss = 0.f;
    #pragma unroll
    for (int e = 0; e < 12; ++e) { pv[e] = __expf(pv[e] - mx); ss += pv[e]; }
    ss += __shfl_xor(ss, 16);
    ss += __shfl_xor(ss, 32);
    const float inv = 1.0f / ss;
    const unsigned t0d0 = (unsigned)f2bf(pv[0]*inv) | ((unsigned)f2bf(pv[1]*inv) << 16);
    const unsigned t0d1 = (unsigned)f2bf(pv[2]*inv) | ((unsigned)f2bf(pv[3]*inv) << 16);
    const unsigned t1d0 = (unsigned)f2bf(pv[4]*inv) | ((unsigned)f2bf(pv[5]*inv) << 16);
    const unsigned t1d1 = (unsigned)f2bf(pv[6]*inv) | ((unsigned)f2bf(pv[7]*inv) << 16);
    const int L0 = (((g << 1) & 3) << 4) | c;
    const int L1 = ((((g << 1) | 1) & 3) << 4) | c;
    const unsigned s00 = (unsigned)__shfl((int)t0d0, L0);
    const unsigned s01 = (unsigned)__shfl((int)t0d1, L0);
    const unsigned s02 = (unsigned)__shfl((int)t1d0, L0);
    const unsigned s03 = (unsigned)__shfl((int)t1d1, L0);
    const unsigned s10 = (unsigned)__shfl((int)t0d0, L1);
    const unsigned s11 = (unsigned)__shfl((int)t0d1, L1);
    const unsigned s12 = (unsigned)__shfl((int)t1d0, L1);
    const unsigned s13 = (unsigned)__shfl((int)t1d1, L1);
    const bool lo2 = (g < 2);
    uint4 av;
    av.x = lo2 ? s00 : s02;
    av.y = lo2 ? s01 : s03;
    av.z = lo2 ? s10 : s12;
    av.w = lo2 ? s11 : s13;
    const short8 pa = __builtin_bit_cast(short8, av);
    f32x4 o = (f32x4){0.f,0.f,0.f,0.f};
    o = __builtin_amdgcn_mfma_f32_16x16x32_bf16(pa, vb8, o, 0,0,0);
    const float p32f = pv[8] * inv;
    #pragma unroll
    for (int r = 0; r < 4; ++r) {
      const float p32 = __shfl(p32f, 4*g + r);
      o[r] += p32 * v32f;
    }
    float* ob = qf + (size_t)n*3168 + h*16 + c;
    #pragma unroll
    for (int r = 0; r < 4; ++r) {
      const int io = it*16 + 4*g + r;
      if (io < 33) ob[(size_t)io*96] = o[r];
    }
  }
}

// ---------------- K3: output projection (per-kstep staging) -------------
__global__ __launch_bounds__(256) void proj_mfma(
    const float* __restrict__ qf, const unsigned* __restrict__ frag,
    const float* __restrict__ bias, float* __restrict__ out) {
  __shared__ __align__(16) unsigned short sBuf[10240];   // 20480 B
  unsigned short* sAh = sBuf;          // [128][40]
  unsigned short* sAl = sBuf + 5120;
  const int tid = threadIdx.x;
  const int w = tid >> 6, l = tid & 63;
  const int m0 = blockIdx.x * 128;
  f32x4 acc[2][6];
  #pragma unroll
  for (int rf = 0; rf < 2; ++rf)
    #pragma unroll
    for (int cf = 0; cf < 6; ++cf) acc[rf][cf] = (f32x4){0.f,0.f,0.f,0.f};

  #pragma unroll
  for (int kstep = 0; kstep < 3; ++kstep) {
    short8 bh[6], bl[6];
    #pragma unroll
    for (int cf = 0; cf < 6; ++cf) {
      const int fph = kstep*12 + cf*2;
      bh[cf] = *(const short8*)(frag + fph*256 + l*4);
      bl[cf] = *(const short8*)(frag + (fph+1)*256 + l*4);
    }
    __syncthreads();
    #pragma unroll
    for (int it2 = 0; it2 < 4; ++it2) {
      const int idx = tid + it2*256;
      const int row = idx >> 3, q = idx & 7;
      const int m = m0 + row;
      const int n = m / 33, t = m - n*33;
      const float4 v = *(const float4*)(qf + (size_t)n*3168 + t*96 + kstep*32 + q*4);
      ushort4 hv, lv;
      hv.x = f2bf(v.x); hv.y = f2bf(v.y); hv.z = f2bf(v.z); hv.w = f2bf(v.w);
      lv.x = f2bf(v.x - bf2f(hv.x)); lv.y = f2bf(v.y - bf2f(hv.y));
      lv.z = f2bf(v.z - bf2f(hv.z)); lv.w = f2bf(v.w - bf2f(hv.w));
      *(ushort4*)&sAh[row*40 + q*4] = hv;
      *(ushort4*)&sAl[row*40 + q*4] = lv;
    }
    __syncthreads();
    #pragma unroll
    for (int rf = 0; rf < 2; ++rf) {
      const int row = w*32 + rf*16 + (l & 15);
      const int off = row*40 + (l >> 4)*8;
      const short8 ah = *(const short8*)&sAh[off];
      const short8 al = *(const short8*)&sAl[off];
      #pragma unroll
      for (int cf = 0; cf < 6; ++cf) {
        acc[rf][cf] = __builtin_amdgcn_mfma_f32_16x16x32_bf16(ah, bh[cf], acc[rf][cf], 0,0,0);
        acc[rf][cf] = __builtin_amdgcn_mfma_f32_16x16x32_bf16(al, bh[cf], acc[rf][cf], 0,0,0);
        acc[rf][cf] = __builtin_amdgcn_mfma_f32_16x16x32_bf16(ah, bl[cf], acc[rf][cf], 0,0,0);
      }
    }
  }
  const int col = l & 15;
  #pragma unroll
  for (int cf = 0; cf < 6; ++cf) {
    const float bv = bias[cf*16 + col];
    #pragma unroll
    for (int rf = 0; rf < 2; ++rf)
      #pragma unroll
      for (int r = 0; r < 4; ++r) {
        const int m = m0 + w*32 + rf*16 + (l >> 4)*4 + r;
        out[(size_t)m*96 + cf*16 + col] = acc[rf][cf][r] + bv;
      }
  }
}

extern "C" void kernel_launch(void* const* d_in, const int* in_sizes, int n_in,
                              void* d_out, int out_size, void* d_ws, size_t ws_size,
                              hipStream_t stream) {
  const float* data   = (const float*)d_in[0];
  const int*   rel    = (const int*)  d_in[1];
  const float* mask   = (const float*)d_in[2];
  const float* qkv_w  = (const float*)d_in[3];
  const float* qkv_b  = (const float*)d_in[4];
  const float* proj_w = (const float*)d_in[5];
  const float* proj_b = (const float*)d_in[6];
  const float* rpet   = (const float*)d_in[7];
  float* qf = (float*)d_ws;                                        // 51.9 MB
  unsigned short* kvh = (unsigned short*)(qf + (size_t)NWIN*3168); // 57.4 MB
  float* out = (float*)d_out;

  conv_w_qkv <<<dim3(108),        256, 0, stream>>>(qkv_w, (unsigned*)d_out);
  q_mfma     <<<dim3(MROWS/128),  256, 0, stream>>>(data, (const unsigned*)d_out, qkv_b, qf);
  kv_mfma    <<<dim3(MROWS/64),   256, 0, stream>>>(data, (const unsigned*)d_out, qkv_b, kvh);
  attn_kernel<<<dim3(NWIN),       384, 0, stream>>>(qf, kvh, rel, mask, rpet);
  conv_w_proj<<<dim3(36),         256, 0, stream>>>(proj_w, (unsigned*)kvh);
  proj_mfma  <<<dim3(MROWS/128),  256, 0, stream>>>(qf, (const unsigned*)kvh, proj_b, out);
}

// Round 21
// 132.980 us; speedup vs baseline: 1.1049x; 1.1049x over previous
//
#include <hip/hip_runtime.h>
#include <cstdint>

// N=4096 windows, T=33, C=96, H=6, HD=16.
// ws layout v5:
//   qf  : fp32 q[n][h][t][d]          4096*3168 floats  = 51.9 MB
//   kvh : bf16, window stride 7008 u16 = K[h][t][d] (3168) + V^T[h][d][t]
//         (row stride 40 u16 -> 640/head, 3840) = 57.4 MB. Total 109.3 MB.
// GEMMs: MFMA 16x16x32 bf16 split-precision (hi+lo), 3-pass qkv (grid.y=3).
// v20: REVERT round-20's q/kv split (latency regression: serial B-load
// groups + extra dispatch; A-traffic was not the binding constraint).
// Back to round-19 set + ONE change: proj_mfma per-kstep staging
// (LDS 53.2KB -> 20.5KB), mirroring the qkv change that won -12us.
// Attn v17 unchanged (MFMA attn, shfl P-repack, uniform bias build).

static constexpr int NWIN = 4096;
static constexpr int MROWS = NWIN * 33;          // 135168 = 1056*128
static constexpr float SCALE = 0.25f;            // HD^-0.5
static constexpr int KVSTRIDE = 7008;            // u16 per window in kvh

using short8 = __attribute__((ext_vector_type(8))) short;
using f32x4  = __attribute__((ext_vector_type(4))) float;

__device__ __forceinline__ unsigned short f2bf(float f) {
  unsigned u = __float_as_uint(f);
  u += 0x7fffu + ((u >> 16) & 1u);
  return (unsigned short)(u >> 16);
}
__device__ __forceinline__ float bf2f(unsigned short h) {
  return __uint_as_float(((unsigned)h) << 16);
}
__device__ __forceinline__ float bflo(unsigned u) { return __uint_as_float(u << 16); }
__device__ __forceinline__ float bfhi(unsigned u) { return __uint_as_float(u & 0xffff0000u); }

// ---------------- K0: qkv_w -> B-fragments in d_out ----------------
__global__ __launch_bounds__(256) void conv_w_qkv(
    const float* __restrict__ W, unsigned* __restrict__ frag) {
  const int fp = blockIdx.x;                     // 108 = 3 ksteps*18 cf*2 hl
  const int kstep = fp / 36;
  const int r = fp - kstep*36;
  const int cf = r >> 1, hl = r & 1;
  const int t = threadIdx.x, lane = t >> 2, d = t & 3;
  const int k = kstep*32 + (lane >> 4)*8 + d*2;
  const int n = cf*16 + (lane & 15);
  float w0 = W[k*288 + n], w1 = W[(k+1)*288 + n];
  if (hl) { w0 -= bf2f(f2bf(w0)); w1 -= bf2f(f2bf(w1)); }
  frag[fp*256 + t] = (unsigned)f2bf(w0) | ((unsigned)f2bf(w1) << 16);
}

// ---------------- K2b: proj_w -> B-fragments at start of (dead) kvh ----
__global__ __launch_bounds__(256) void conv_w_proj(
    const float* __restrict__ W, unsigned* __restrict__ frag) {
  const int fp = blockIdx.x;                     // 36 = 3 ksteps*6 cf*2 hl
  const int kstep = fp / 12;
  const int r = fp - kstep*12;
  const int cf = r >> 1, hl = r & 1;
  const int t = threadIdx.x, lane = t >> 2, d = t & 3;
  const int k = kstep*32 + (lane >> 4)*8 + d*2;
  const int n = cf*16 + (lane & 15);
  float w0 = W[k*96 + n], w1 = W[(k+1)*96 + n];
  if (hl) { w0 -= bf2f(f2bf(w0)); w1 -= bf2f(f2bf(w1)); }
  frag[fp*256 + t] = (unsigned)f2bf(w0) | ((unsigned)f2bf(w1) << 16);
}

// ---------------- K1: QKV projection, split-bf16 MFMA (3-pass) ----------
// grid (1056, 3), block 256. s: 0=q (fp32), 1=k (bf16 [h][t][d]),
// 2=v (bf16 TRANSPOSED [h][d][t], row stride 40) via LDS re-stage.
// Per-kstep A staging: sAh/sAl [128][40] u16 chunks in a 13056-u16 buffer.
__global__ __launch_bounds__(256) void qkv_mfma(
    const float* __restrict__ A, const unsigned* __restrict__ frag,
    const float* __restrict__ bias, float* __restrict__ qf,
    unsigned short* __restrict__ kvh) {
  __shared__ __align__(16) unsigned short sBuf[13056];   // 26112 B
  unsigned short* sAh = sBuf;          // [128][40] (5120 u16)
  unsigned short* sAl = sBuf + 5120;   // [128][40]
  const int tid = threadIdx.x;
  const int w = tid >> 6, l = tid & 63;
  const int m0 = blockIdx.x * 128;
  const int s = blockIdx.y;
  f32x4 acc[2][6];
  #pragma unroll
  for (int rf = 0; rf < 2; ++rf)
    #pragma unroll
    for (int cf = 0; cf < 6; ++cf) acc[rf][cf] = (f32x4){0.f,0.f,0.f,0.f};

  #pragma unroll
  for (int kstep = 0; kstep < 3; ++kstep) {
    // B-fragment loads: independent of LDS, issue before the barrier
    short8 bh[6], bl[6];
    #pragma unroll
    for (int cf = 0; cf < 6; ++cf) {
      const int fp = (kstep*18 + s*6 + cf)*2;
      bh[cf] = *(const short8*)((const char*)frag + (size_t)fp*1024 + l*16);
      bl[cf] = *(const short8*)((const char*)frag + (size_t)fp*1024 + 1024 + l*16);
    }
    __syncthreads();     // previous chunk's reads complete before overwrite
    #pragma unroll
    for (int it2 = 0; it2 < 4; ++it2) {
      const int idx = tid + it2*256;               // 0..1023
      const int row = idx >> 3, q = idx & 7;       // 128 rows x 8 float4
      const float4 v = *(const float4*)(A + (size_t)(m0+row)*96 + kstep*32 + q*4);
      ushort4 hv, lv;
      hv.x = f2bf(v.x); hv.y = f2bf(v.y); hv.z = f2bf(v.z); hv.w = f2bf(v.w);
      lv.x = f2bf(v.x - bf2f(hv.x)); lv.y = f2bf(v.y - bf2f(hv.y));
      lv.z = f2bf(v.z - bf2f(hv.z)); lv.w = f2bf(v.w - bf2f(hv.w));
      *(ushort4*)&sAh[row*40 + q*4] = hv;
      *(ushort4*)&sAl[row*40 + q*4] = lv;
    }
    __syncthreads();
    #pragma unroll
    for (int rf = 0; rf < 2; ++rf) {
      const int row = w*32 + rf*16 + (l & 15);
      const int off = row*40 + (l >> 4)*8;
      const short8 ah = *(const short8*)&sAh[off];
      const short8 al = *(const short8*)&sAl[off];
      #pragma unroll
      for (int cf = 0; cf < 6; ++cf) {
        acc[rf][cf] = __builtin_amdgcn_mfma_f32_16x16x32_bf16(ah, bh[cf], acc[rf][cf], 0,0,0);
        acc[rf][cf] = __builtin_amdgcn_mfma_f32_16x16x32_bf16(al, bh[cf], acc[rf][cf], 0,0,0);
        acc[rf][cf] = __builtin_amdgcn_mfma_f32_16x16x32_bf16(ah, bl[cf], acc[rf][cf], 0,0,0);
      }
    }
  }
  const int col = l & 15;
  if (s == 0) {
    #pragma unroll
    for (int cf = 0; cf < 6; ++cf) {
      const float bv = bias[cf*16 + col];
      #pragma unroll
      for (int rf = 0; rf < 2; ++rf)
        #pragma unroll
        for (int r = 0; r < 4; ++r) {
          const int m = m0 + w*32 + rf*16 + (l >> 4)*4 + r;
          const int n = m / 33, t = m - n*33;
          qf[(size_t)n*3168 + cf*528 + t*16 + col] = (acc[rf][cf][r] + bv)*SCALE;
        }
    }
  } else if (s == 1) {
    #pragma unroll
    for (int cf = 0; cf < 6; ++cf) {
      const float bv = bias[96 + cf*16 + col];
      #pragma unroll
      for (int rf = 0; rf < 2; ++rf)
        #pragma unroll
        for (int r = 0; r < 4; ++r) {
          const int m = m0 + w*32 + rf*16 + (l >> 4)*4 + r;
          const int n = m / 33, t = m - n*33;
          kvh[(size_t)n*KVSTRIDE + cf*528 + t*16 + col] = f2bf(acc[rf][cf][r] + bv);
        }
    }
  } else {
    // V: stage acc into LDS (whole sBuf; main-loop reads done), then
    // coalesced V^T write-out (consecutive threads -> consecutive t).
    __syncthreads();
    unsigned short* sV = sBuf;                 // [128][102] u16 (13056)
    #pragma unroll
    for (int cf = 0; cf < 6; ++cf) {
      const float bv = bias[192 + cf*16 + col];
      #pragma unroll
      for (int rf = 0; rf < 2; ++rf)
        #pragma unroll
        for (int r = 0; r < 4; ++r) {
          const int row = w*32 + rf*16 + (l >> 4)*4 + r;
          sV[row*102 + cf*16 + col] = f2bf(acc[rf][cf][r] + bv);
        }
    }
    __syncthreads();
    for (int idx = tid; idx < 12288; idx += 256) {
      const int hd = idx >> 7, trow = idx & 127;
      const int m = m0 + trow;
      const int n = m / 33, t = m - n*33;
      kvh[(size_t)n*KVSTRIDE + 3168 + (hd >> 4)*640 + (hd & 15)*40 + t] =
          sV[trow*102 + hd];
    }
  }
}

// ---------------- K2: per-window MFMA attention (v17, unchanged) --------
// grid 4096, block 384 (6 waves, wave = head).
__global__ __launch_bounds__(384) void attn_kernel(
    float* __restrict__ qf, const unsigned short* __restrict__ kvh,
    const int* __restrict__ rel, const float* __restrict__ mask,
    const float* __restrict__ rpet) {
  __shared__ __align__(8) unsigned short sBiasH[7168]; // [h][i][36] + guard
  __shared__ __align__(4) unsigned short sRpe6[920];   // [153][6] bf16
  const int tid = threadIdx.x;
  const int n = blockIdx.x;
  const int l = tid & 63, g = l >> 4, c = l & 15, h = tid >> 6;
  const unsigned short* Kb = kvh + (size_t)n*KVSTRIDE + h*528;
  const unsigned short* Vb = kvh + (size_t)n*KVSTRIDE + 3168 + h*640;
  const float*          Qb = qf  + (size_t)n*3168 + h*528;
  short8 ka[3];
  #pragma unroll
  for (int jt = 0; jt < 3; ++jt)
    ka[jt] = *(const short8*)(Kb + (jt*16 + c)*16 + (g & 1)*8); // K[j][d]
  const short8 vb8 = *(const short8*)(Vb + c*40 + g*8);         // V[j=8g+e][d=c]
  const unsigned short v32u = Vb[c*40 + 32];                    // V[32][d=c]
  float4 qa_[3], qc_[3];
  #pragma unroll
  for (int it = 0; it < 3; ++it) {
    const int i = it*16 + c;
    qa_[it] = make_float4(0.f,0.f,0.f,0.f);
    qc_[it] = make_float4(0.f,0.f,0.f,0.f);
    if (i < 33) {
      qa_[it] = *(const float4*)(Qb + i*16 + (g & 1)*8);
      qc_[it] = *(const float4*)(Qb + i*16 + (g & 1)*8 + 4);
    }
  }
  for (int idx = tid; idx < 918; idx += 384) sRpe6[idx] = f2bf(rpet[idx]);
  __syncthreads();
  {
    const float* gm = mask + (size_t)n*1089;
    const int*   rb = rel  + (size_t)n*3072;
    const unsigned* rp6 = (const unsigned*)sRpe6;
    int   ee[3];
    bool  act[3], rpok[3];
    float mv[3];
    int   xx[3][3];
    #pragma unroll
    for (int q2 = 0; q2 < 3; ++q2) {
      int e = tid + q2*384;
      act[q2] = (e < 1089);
      if (!act[q2]) e = 0;
      ee[q2] = e;
      const int i = e / 33, j = e - i*33;
      rpok[q2] = (i > 0) && (j > 0);
      const int rbase = rpok[q2] ? ((i-1)*32 + (j-1))*3 : 0;
      mv[q2]    = gm[e];
      xx[q2][0] = rb[rbase]*3;
      xx[q2][1] = (rb[rbase+1] + 51)*3;
      xx[q2][2] = (rb[rbase+2] + 102)*3;
    }
    #pragma unroll
    for (int q2 = 0; q2 < 3; ++q2) {
      float b0=0.f, b1=0.f, b2=0.f, b3=0.f, b4=0.f, b5=0.f;
      #pragma unroll
      for (int a = 0; a < 3; ++a) {
        const unsigned u0 = rp6[xx[q2][a]];
        const unsigned u1 = rp6[xx[q2][a]+1];
        const unsigned u2 = rp6[xx[q2][a]+2];
        b0 += bflo(u0); b1 += bfhi(u0);
        b2 += bflo(u1); b3 += bfhi(u1);
        b4 += bflo(u2); b5 += bfhi(u2);
      }
      const float m2 = mv[q2];
      const bool ok = rpok[q2];
      b0 = ok ? b0 + m2 : m2;  b1 = ok ? b1 + m2 : m2;
      b2 = ok ? b2 + m2 : m2;  b3 = ok ? b3 + m2 : m2;
      b4 = ok ? b4 + m2 : m2;  b5 = ok ? b5 + m2 : m2;
      if (act[q2]) {
        const int e = ee[q2];
        const int i = e / 33, j = e - i*33;
        const int bb = i*36 + j;
        sBiasH[bb]        = f2bf(b0);
        sBiasH[bb + 1188] = f2bf(b1);
        sBiasH[bb + 2376] = f2bf(b2);
        sBiasH[bb + 3564] = f2bf(b3);
        sBiasH[bb + 4752] = f2bf(b4);
        sBiasH[bb + 5940] = f2bf(b5);
      }
    }
  }
  const float v32f = bf2f(v32u);
  short8 qfr[3];
  #pragma unroll
  for (int it = 0; it < 3; ++it) {
    const float qv[8] = {qa_[it].x, qa_[it].y, qa_[it].z, qa_[it].w,
                         qc_[it].x, qc_[it].y, qc_[it].z, qc_[it].w};
    short8 t;
    #pragma unroll
    for (int e = 0; e < 8; ++e) {
      const unsigned short hi = f2bf(qv[e]);
      const unsigned short lo = f2bf(qv[e] - bf2f(hi));
      t[e] = (short)((g < 2) ? hi : lo);
    }
    qfr[it] = t;
  }
  __syncthreads();
  const int hbase = h*1188;
  #pragma unroll
  for (int it = 0; it < 3; ++it) {
    const int i  = it*16 + c;
    const int bi = (i < 33) ? i : 0;
    const int bbase = hbase + bi*36;
    float pv[12];
    float mx = -3.4e38f;
    #pragma unroll
    for (int jt = 0; jt < 3; ++jt) {
      const ushort4 bv4 = *(const ushort4*)(sBiasH + bbase + jt*16 + 4*g);
      f32x4 sacc;
      sacc[0] = bf2f(bv4.x); sacc[1] = bf2f(bv4.y);
      sacc[2] = bf2f(bv4.z); sacc[3] = bf2f(bv4.w);
      sacc = __builtin_amdgcn_mfma_f32_16x16x32_bf16(ka[jt], qfr[it], sacc, 0,0,0);
      #pragma unroll
      for (int r = 0; r < 4; ++r) {
        const int j = jt*16 + 4*g + r;
        float sv = sacc[r];
        if (j >= 33) sv = -3.4e38f;
        pv[jt*4+r] = sv;
        mx = fmaxf(mx, sv);
      }
    }
    mx = fmaxf(mx, __shfl_xor(mx, 16));
    mx = fmaxf(mx, __shfl_xor(mx, 32));
    float ss = 0.f;
    #pragma unroll
    for (int e = 0; e < 12; ++e) { pv[e] = __expf(pv[e] - mx); ss += pv[e]; }
    ss += __shfl_xor(ss, 16);
    ss += __shfl_xor(ss, 32);
    const float inv = 1.0f / ss;
    const unsigned t0d0 = (unsigned)f2bf(pv[0]*inv) | ((unsigned)f2bf(pv[1]*inv) << 16);
    const unsigned t0d1 = (unsigned)f2bf(pv[2]*inv) | ((unsigned)f2bf(pv[3]*inv) << 16);
    const unsigned t1d0 = (unsigned)f2bf(pv[4]*inv) | ((unsigned)f2bf(pv[5]*inv) << 16);
    const unsigned t1d1 = (unsigned)f2bf(pv[6]*inv) | ((unsigned)f2bf(pv[7]*inv) << 16);
    const int L0 = (((g << 1) & 3) << 4) | c;
    const int L1 = ((((g << 1) | 1) & 3) << 4) | c;
    const unsigned s00 = (unsigned)__shfl((int)t0d0, L0);
    const unsigned s01 = (unsigned)__shfl((int)t0d1, L0);
    const unsigned s02 = (unsigned)__shfl((int)t1d0, L0);
    const unsigned s03 = (unsigned)__shfl((int)t1d1, L0);
    const unsigned s10 = (unsigned)__shfl((int)t0d0, L1);
    const unsigned s11 = (unsigned)__shfl((int)t0d1, L1);
    const unsigned s12 = (unsigned)__shfl((int)t1d0, L1);
    const unsigned s13 = (unsigned)__shfl((int)t1d1, L1);
    const bool lo2 = (g < 2);
    uint4 av;
    av.x = lo2 ? s00 : s02;
    av.y = lo2 ? s01 : s03;
    av.z = lo2 ? s10 : s12;
    av.w = lo2 ? s11 : s13;
    const short8 pa = __builtin_bit_cast(short8, av);
    f32x4 o = (f32x4){0.f,0.f,0.f,0.f};
    o = __builtin_amdgcn_mfma_f32_16x16x32_bf16(pa, vb8, o, 0,0,0);
    const float p32f = pv[8] * inv;
    #pragma unroll
    for (int r = 0; r < 4; ++r) {
      const float p32 = __shfl(p32f, 4*g + r);
      o[r] += p32 * v32f;
    }
    float* ob = qf + (size_t)n*3168 + h*16 + c;
    #pragma unroll
    for (int r = 0; r < 4; ++r) {
      const int io = it*16 + 4*g + r;
      if (io < 33) ob[(size_t)io*96] = o[r];
    }
  }
}

// ---------------- K3: output projection (per-kstep staging) -------------
__global__ __launch_bounds__(256) void proj_mfma(
    const float* __restrict__ qf, const unsigned* __restrict__ frag,
    const float* __restrict__ bias, float* __restrict__ out) {
  __shared__ __align__(16) unsigned short sBuf[10240];   // 20480 B
  unsigned short* sAh = sBuf;          // [128][40]
  unsigned short* sAl = sBuf + 5120;
  const int tid = threadIdx.x;
  const int w = tid >> 6, l = tid & 63;
  const int m0 = blockIdx.x * 128;
  f32x4 acc[2][6];
  #pragma unroll
  for (int rf = 0; rf < 2; ++rf)
    #pragma unroll
    for (int cf = 0; cf < 6; ++cf) acc[rf][cf] = (f32x4){0.f,0.f,0.f,0.f};

  #pragma unroll
  for (int kstep = 0; kstep < 3; ++kstep) {
    short8 bh[6], bl[6];
    #pragma unroll
    for (int cf = 0; cf < 6; ++cf) {
      const int fph = kstep*12 + cf*2;
      bh[cf] = *(const short8*)(frag + fph*256 + l*4);
      bl[cf] = *(const short8*)(frag + (fph+1)*256 + l*4);
    }
    __syncthreads();
    #pragma unroll
    for (int it2 = 0; it2 < 4; ++it2) {
      const int idx = tid + it2*256;
      const int row = idx >> 3, q = idx & 7;
      const int m = m0 + row;
      const int n = m / 33, t = m - n*33;
      const float4 v = *(const float4*)(qf + (size_t)n*3168 + t*96 + kstep*32 + q*4);
      ushort4 hv, lv;
      hv.x = f2bf(v.x); hv.y = f2bf(v.y); hv.z = f2bf(v.z); hv.w = f2bf(v.w);
      lv.x = f2bf(v.x - bf2f(hv.x)); lv.y = f2bf(v.y - bf2f(hv.y));
      lv.z = f2bf(v.z - bf2f(hv.z)); lv.w = f2bf(v.w - bf2f(hv.w));
      *(ushort4*)&sAh[row*40 + q*4] = hv;
      *(ushort4*)&sAl[row*40 + q*4] = lv;
    }
    __syncthreads();
    #pragma unroll
    for (int rf = 0; rf < 2; ++rf) {
      const int row = w*32 + rf*16 + (l & 15);
      const int off = row*40 + (l >> 4)*8;
      const short8 ah = *(const short8*)&sAh[off];
      const short8 al = *(const short8*)&sAl[off];
      #pragma unroll
      for (int cf = 0; cf < 6; ++cf) {
        acc[rf][cf] = __builtin_amdgcn_mfma_f32_16x16x32_bf16(ah, bh[cf], acc[rf][cf], 0,0,0);
        acc[rf][cf] = __builtin_amdgcn_mfma_f32_16x16x32_bf16(al, bh[cf], acc[rf][cf], 0,0,0);
        acc[rf][cf] = __builtin_amdgcn_mfma_f32_16x16x32_bf16(ah, bl[cf], acc[rf][cf], 0,0,0);
      }
    }
  }
  const int col = l & 15;
  #pragma unroll
  for (int cf = 0; cf < 6; ++cf) {
    const float bv = bias[cf*16 + col];
    #pragma unroll
    for (int rf = 0; rf < 2; ++rf)
      #pragma unroll
      for (int r = 0; r < 4; ++r) {
        const int m = m0 + w*32 + rf*16 + (l >> 4)*4 + r;
        out[(size_t)m*96 + cf*16 + col] = acc[rf][cf][r] + bv;
      }
  }
}

extern "C" void kernel_launch(void* const* d_in, const int* in_sizes, int n_in,
                              void* d_out, int out_size, void* d_ws, size_t ws_size,
                              hipStream_t stream) {
  const float* data   = (const float*)d_in[0];
  const int*   rel    = (const int*)  d_in[1];
  const float* mask   = (const float*)d_in[2];
  const float* qkv_w  = (const float*)d_in[3];
  const float* qkv_b  = (const float*)d_in[4];
  const float* proj_w = (const float*)d_in[5];
  const float* proj_b = (const float*)d_in[6];
  const float* rpet   = (const float*)d_in[7];
  float* qf = (float*)d_ws;                                        // 51.9 MB
  unsigned short* kvh = (unsigned short*)(qf + (size_t)NWIN*3168); // 57.4 MB
  float* out = (float*)d_out;

  conv_w_qkv <<<dim3(108),          256, 0, stream>>>(qkv_w, (unsigned*)d_out);
  qkv_mfma   <<<dim3(MROWS/128, 3), 256, 0, stream>>>(data, (const unsigned*)d_out, qkv_b, qf, kvh);
  attn_kernel<<<dim3(NWIN),         384, 0, stream>>>(qf, kvh, rel, mask, rpet);
  conv_w_proj<<<dim3(36),           256, 0, stream>>>(proj_w, (unsigned*)kvh);
  proj_mfma  <<<dim3(MROWS/128),    256, 0, stream>>>(qf, (const unsigned*)kvh, proj_b, out);
}